// Round 1
// baseline (117.519 us; speedup 1.0000x reference)
//
#include <hip/hip_runtime.h>

#define IN_DIM 128
#define OUT_DIM 32
#define NHEAD 2

// Kernel 1: init D=1 (self-loop dist 1), cnt=1 (self-loop), and reduce W -> wsum[h][j] = sum_o W[h,j,o]
__global__ void k_init(const float* __restrict__ W, float* __restrict__ wsum,
                       float* __restrict__ D, float* __restrict__ cnt, int N) {
    int i = blockIdx.x * blockDim.x + threadIdx.x;
    if (i < NHEAD * IN_DIM) {
        const float* wp = W + i * OUT_DIM;   // (h*128+j)*32
        float s = 0.f;
        #pragma unroll
        for (int o = 0; o < OUT_DIM; ++o) s += wp[o];
        wsum[i] = s;
    }
    if (i < N) { D[i] = 1.0f; cnt[i] = 1.0f; }
}

// Kernel 2: per original edge, accumulate 1/max(dist,1e-6) and count into source node
__global__ void k_edges(const int* __restrict__ row, const int* __restrict__ col,
                        const float* __restrict__ pos,
                        float* __restrict__ D, float* __restrict__ cnt, int E) {
    int e = blockIdx.x * blockDim.x + threadIdx.x;
    if (e >= E) return;
    int r = row[e], c = col[e];
    float dx = pos[c * 3 + 0] - pos[r * 3 + 0];
    float dy = pos[c * 3 + 1] - pos[r * 3 + 1];
    float dz = pos[c * 3 + 2] - pos[r * 3 + 2];
    float d = sqrtf(dx * dx + dy * dy + dz * dz);
    float inv = 1.0f / fmaxf(d, 1e-6f);
    atomicAdd(&D[r], inv);
    atomicAdd(&cnt[r], 1.0f);
}

// Kernel 3: node[h,i] = 2 * dot(x[i], wsum[h]) * D[i] / cnt[i]
// 16 lanes cooperate per node: each lane reads 2 float4 of x (coalesced per group).
__global__ void k_node(const float* __restrict__ x, const float* __restrict__ wsum,
                       const float* __restrict__ D, const float* __restrict__ cnt,
                       float* __restrict__ node, int N) {
    int gid = blockIdx.x * blockDim.x + threadIdx.x;
    int i = gid >> 4;
    int lid = gid & 15;
    if (i >= N) return;
    const float4* xp = (const float4*)(x + (long)i * IN_DIM);
    const float4* w0 = (const float4*)(wsum);
    const float4* w1 = (const float4*)(wsum + IN_DIM);
    float s0 = 0.f, s1 = 0.f;
    #pragma unroll
    for (int q = 0; q < 2; ++q) {
        int idx = lid * 2 + q;           // float4 index in [0,32)
        float4 xv = xp[idx];
        float4 a = w0[idx];
        float4 b = w1[idx];
        s0 += xv.x * a.x + xv.y * a.y + xv.z * a.z + xv.w * a.w;
        s1 += xv.x * b.x + xv.y * b.y + xv.z * b.z + xv.w * b.w;
    }
    #pragma unroll
    for (int off = 8; off >= 1; off >>= 1) {
        s0 += __shfl_xor(s0, off, 16);
        s1 += __shfl_xor(s1, off, 16);
    }
    if (lid == 0) {
        float f = 2.0f * D[i] / cnt[i];
        node[i]     = s0 * f;
        node[N + i] = s1 * f;
    }
}

// Kernel 4: out[h*M+k] = node[h,row2[k]] - node[h,col2[k]]; self-loop entries (k>=E) are exactly 0.
__global__ void k_out(const int* __restrict__ row, const int* __restrict__ col,
                      const float* __restrict__ node,
                      float* __restrict__ out, int N, int E, int M) {
    int k = blockIdx.x * blockDim.x + threadIdx.x;
    if (k >= M) return;
    float o0 = 0.f, o1 = 0.f;
    if (k < E) {
        int r = row[k], c = col[k];
        o0 = node[r] - node[c];
        o1 = node[N + r] - node[N + c];
    }
    out[k]     = o0;
    out[M + k] = o1;
}

extern "C" void kernel_launch(void* const* d_in, const int* in_sizes, int n_in,
                              void* d_out, int out_size, void* d_ws, size_t ws_size,
                              hipStream_t stream) {
    const float* x   = (const float*)d_in[0];
    const float* pos = (const float*)d_in[1];
    const float* W   = (const float*)d_in[2];
    // d_in[3] (attn) is mathematically unused: softmax over constant-per-segment logits = 1/count.
    const int* row = (const int*)d_in[4];
    const int* col = (const int*)d_in[5];
    float* out = (float*)d_out;

    const int N = in_sizes[0] / IN_DIM;
    const int E = in_sizes[4];
    const int M = E + N;

    float* wsp  = (float*)d_ws;
    float* wsum = wsp;                 // 256 floats
    float* D    = wsp + 256;           // N floats
    float* cnt  = wsp + 256 + N;       // N floats (counts are small ints, exact in fp32)
    float* node = wsp + 256 + 2 * N;   // 2N floats

    const int b = 256;
    int g_init = (max(N, NHEAD * IN_DIM) + b - 1) / b;
    k_init <<<g_init,                b, 0, stream>>>(W, wsum, D, cnt, N);
    k_edges<<<(E + b - 1) / b,       b, 0, stream>>>(row, col, pos, D, cnt, E);
    k_node <<<(N * 16 + b - 1) / b,  b, 0, stream>>>(x, wsum, D, cnt, node, N);
    k_out  <<<(M + b - 1) / b,       b, 0, stream>>>(row, col, node, out, N, E, M);
}

// Round 2
// 73.311 us; speedup vs baseline: 1.6030x; 1.6030x over previous
//
#include <hip/hip_runtime.h>

#define IN_DIM 128
#define OUT_DIM 32
#define NHEAD 2
#define FIX_SCALE 1048576.0f      // 2^20 fixed-point for invsum
#define CNT_SHIFT 44              // count lives in bits [44,63]

// Kernel 1: zero the packed accumulators; reduce W -> wsum[h][j] = sum_o W[h,j,o]
__global__ void k_init(const float* __restrict__ W, float* __restrict__ wsum,
                       unsigned long long* __restrict__ packed, int total_packed) {
    int i = blockIdx.x * blockDim.x + threadIdx.x;
    if (i < NHEAD * IN_DIM) {
        const float* wp = W + i * OUT_DIM;
        float s = 0.f;
        #pragma unroll
        for (int o = 0; o < OUT_DIM; ++o) s += wp[o];
        wsum[i] = s;
    }
    if (i < total_packed) packed[i] = 0ull;
}

// Kernel 2: one u64 atomic per edge into an XCD-private copy.
// v = (1 << 44) | round(inv * 2^20); fields can't cross-carry for realistic degree/inv.
__global__ void k_edges(const int* __restrict__ row, const int* __restrict__ col,
                        const float* __restrict__ pos,
                        unsigned long long* __restrict__ packed, int N, int E, int cmask) {
    int e = blockIdx.x * blockDim.x + threadIdx.x;
    if (e >= E) return;
    int r = row[e], c = col[e];
    float dx = pos[c * 3 + 0] - pos[r * 3 + 0];
    float dy = pos[c * 3 + 1] - pos[r * 3 + 1];
    float dz = pos[c * 3 + 2] - pos[r * 3 + 2];
    float d = sqrtf(dx * dx + dy * dy + dz * dz);
    float inv = 1.0f / fmaxf(d, 1e-6f);
    unsigned long long v = (1ull << CNT_SHIFT) + (unsigned long long)(inv * FIX_SCALE);
    // blockIdx.x & cmask ~ XCD id (round-robin dispatch): keeps each copy's lines XCD-local
    atomicAdd(&packed[(long)(blockIdx.x & cmask) * N + r], v);
}

// Kernel 3: fold C copies, decode -> f[i] = 2 * (1 + invsum) / (1 + count)
__global__ void k_factor(const unsigned long long* __restrict__ packed,
                         float* __restrict__ f, int N, int C) {
    int i = blockIdx.x * blockDim.x + threadIdx.x;
    if (i >= N) return;
    unsigned long long v = 0ull;
    for (int c = 0; c < C; ++c) v += packed[(long)c * N + i];
    float invsum = (float)((double)(v & ((1ull << CNT_SHIFT) - 1)) * (1.0 / (double)FIX_SCALE));
    float cnt = 1.0f + (float)(unsigned int)(v >> CNT_SHIFT);
    f[i] = 2.0f * (1.0f + invsum) / cnt;
}

// Kernel 4: node[h,i] = dot(x[i], wsum[h]) * f[i]; 16 lanes per node, float4 coalesced.
__global__ void k_node(const float* __restrict__ x, const float* __restrict__ wsum,
                       const float* __restrict__ f,
                       float* __restrict__ node, int N) {
    int gid = blockIdx.x * blockDim.x + threadIdx.x;
    int i = gid >> 4;
    int lid = gid & 15;
    if (i >= N) return;
    const float4* xp = (const float4*)(x + (long)i * IN_DIM);
    const float4* w0 = (const float4*)(wsum);
    const float4* w1 = (const float4*)(wsum + IN_DIM);
    float s0 = 0.f, s1 = 0.f;
    #pragma unroll
    for (int q = 0; q < 2; ++q) {
        int idx = lid * 2 + q;
        float4 xv = xp[idx];
        float4 a = w0[idx];
        float4 b = w1[idx];
        s0 += xv.x * a.x + xv.y * a.y + xv.z * a.z + xv.w * a.w;
        s1 += xv.x * b.x + xv.y * b.y + xv.z * b.z + xv.w * b.w;
    }
    #pragma unroll
    for (int off = 8; off >= 1; off >>= 1) {
        s0 += __shfl_xor(s0, off, 16);
        s1 += __shfl_xor(s1, off, 16);
    }
    if (lid == 0) {
        float fac = f[i];
        node[i]     = s0 * fac;
        node[N + i] = s1 * fac;
    }
}

// Kernel 5: out[h*M+k] = node[h,row2[k]] - node[h,col2[k]]; self-loop tail is exactly 0.
__global__ void k_out(const int* __restrict__ row, const int* __restrict__ col,
                      const float* __restrict__ node,
                      float* __restrict__ out, int N, int E, int M) {
    int k = blockIdx.x * blockDim.x + threadIdx.x;
    if (k >= M) return;
    float o0 = 0.f, o1 = 0.f;
    if (k < E) {
        int r = row[k], c = col[k];
        o0 = node[r] - node[c];
        o1 = node[N + r] - node[N + c];
    }
    out[k]     = o0;
    out[M + k] = o1;
}

extern "C" void kernel_launch(void* const* d_in, const int* in_sizes, int n_in,
                              void* d_out, int out_size, void* d_ws, size_t ws_size,
                              hipStream_t stream) {
    const float* x   = (const float*)d_in[0];
    const float* pos = (const float*)d_in[1];
    const float* W   = (const float*)d_in[2];
    // d_in[3] (attn) unused: per-segment logits are identical -> softmax = 1/count.
    const int* row = (const int*)d_in[4];
    const int* col = (const int*)d_in[5];
    float* out = (float*)d_out;

    const int N = in_sizes[0] / IN_DIM;
    const int E = in_sizes[4];
    const int M = E + N;

    // Pick copy count C (power of 2, up to 8) that fits the workspace.
    int C = 8;
    while (C > 1 && ((size_t)C * N * 8 + (size_t)(256 + 3 * N) * 4) > ws_size) C >>= 1;

    unsigned long long* packed = (unsigned long long*)d_ws;  // C*N u64
    float* rest = (float*)(packed + (size_t)C * N);
    float* wsum = rest;             // 256
    float* f    = rest + 256;       // N
    float* node = rest + 256 + N;   // 2N

    const int b = 256;
    const int total_packed = C * N;
    k_init  <<<(max(total_packed, NHEAD * IN_DIM) + b - 1) / b, b, 0, stream>>>(W, wsum, packed, total_packed);
    k_edges <<<(E + b - 1) / b,      b, 0, stream>>>(row, col, pos, packed, N, E, C - 1);
    k_factor<<<(N + b - 1) / b,      b, 0, stream>>>(packed, f, N, C);
    k_node  <<<(N * 16 + b - 1) / b, b, 0, stream>>>(x, wsum, f, node, N);
    k_out   <<<(M + b - 1) / b,      b, 0, stream>>>(row, col, node, out, N, E, M);
}